// Round 1
// baseline (294.580 us; speedup 1.0000x reference)
//
#include <hip/hip_runtime.h>

// NonLinearQuantizer: dq = s * NN_codebook(clip(rint((x - z)/s), 0, 31)) + z
// Codebook {15.5 ±8 ±4 ±2} == {1.5 + 4k, k=0..7}; for integral q in [0,31]
// the nearest entry is exactly k = floor(q/4)  (no ties: q integer, midpoints
// are half-integers). So c = 4*floor(q*0.25) + 1.5, all exact in fp32.

constexpr int N_ROWS = 4096;
constexpr int K_COLS = 11008;
constexpr int K4     = K_COLS / 4;  // 2752 float4 per row

__device__ __forceinline__ float dq1(float xv, float s, float z) {
    // IEEE fp32 division (matches jax fp32), rintf = round-half-even (matches jnp.round)
    float q = rintf((xv - z) / s);
    q = fminf(fmaxf(q, 0.0f), 31.0f);
    float c = 4.0f * floorf(q * 0.25f) + 1.5f;  // exact: q*0.25 and floor exact for small ints
    return s * c + z;
}

__global__ __launch_bounds__(256) void nlq_kernel(
    const float* __restrict__ x,
    const float* __restrict__ scale,
    const float* __restrict__ zero,
    float* __restrict__ out)
{
    const unsigned row = blockIdx.y;                       // wave-uniform
    const unsigned c4  = blockIdx.x * 256u + threadIdx.x;  // float4 column index
    if (c4 >= (unsigned)K4) return;

    const float s = scale[row];   // uniform -> scalar load, L2-resident
    const float z = zero[row];

    const unsigned off = row * (unsigned)K_COLS + 4u * c4; // < 2^26, fits u32
    const float4 xv = *reinterpret_cast<const float4*>(x + off);

    float4 o;
    o.x = dq1(xv.x, s, z);
    o.y = dq1(xv.y, s, z);
    o.z = dq1(xv.z, s, z);
    o.w = dq1(xv.w, s, z);

    *reinterpret_cast<float4*>(out + off) = o;
}

extern "C" void kernel_launch(void* const* d_in, const int* in_sizes, int n_in,
                              void* d_out, int out_size, void* d_ws, size_t ws_size,
                              hipStream_t stream) {
    const float* x     = (const float*)d_in[0];
    const float* scale = (const float*)d_in[1];
    const float* zero  = (const float*)d_in[2];
    // d_in[3] = codebook (values baked into the kernel), d_in[4] = maxq (=31)
    float* out = (float*)d_out;

    dim3 block(256);
    dim3 grid((K4 + 255) / 256, N_ROWS);  // 11 x 4096 blocks
    nlq_kernel<<<grid, block, 0, stream>>>(x, scale, zero, out);
}

// Round 3
// 288.600 us; speedup vs baseline: 1.0207x; 1.0207x over previous
//
#include <hip/hip_runtime.h>

// NonLinearQuantizer: dq = s * NN_codebook(clip(rint((x - z)/s), 0, 31)) + z
// Codebook {15.5 ±8 ±4 ±2} == {1.5 + 4k, k=0..7}; for integral q in [0,31]
// the nearest entry is exactly k = floor(q/4) (no ties: q is an integer,
// codebook midpoints are half-integers). So c = 4*floor(q*0.25) + 1.5,
// all exact in fp32. IEEE div + rintf (half-even) match jax fp32 exactly
// -> absmax 0.
//
// Memory-bound: 180.4 MB read + 180.4 MB write, floor ~57 us @ 6.3 TB/s.
// Flat float4 grid: 4096*2752 = 11,272,192 float4 = 44032 blocks x 256,
// zero idle lanes, no bounds check. row = idx/2752 via compiler magic-div;
// 2752 % 64 == 0 so row is wave-uniform (s/z loads broadcast from L1/L2).
// Nontemporal (nt) load/store: zero-reuse streams, don't thrash L2/L3.
// NOTE: __builtin_nontemporal_* needs a NATIVE vector type, not HIP's
// struct float4 -> use ext_vector_type(4).

typedef float f32x4 __attribute__((ext_vector_type(4)));

constexpr int N_ROWS   = 4096;
constexpr int K_COLS   = 11008;
constexpr unsigned K4   = K_COLS / 4;             // 2752 float4 per row
constexpr unsigned TOT4 = (unsigned)N_ROWS * K4;  // 11,272,192
constexpr unsigned BLK  = 256;
constexpr unsigned GRID = TOT4 / BLK;             // 44032, exact

__device__ __forceinline__ float dq1(float xv, float s, float z) {
    float q = rintf((xv - z) / s);             // IEEE div, round-half-even
    q = fminf(fmaxf(q, 0.0f), 31.0f);
    float c = 4.0f * floorf(q * 0.25f) + 1.5f; // exact for integral q in [0,31]
    return s * c + z;
}

__global__ __launch_bounds__(BLK) void nlq_kernel(
    const float* __restrict__ x,
    const float* __restrict__ scale,
    const float* __restrict__ zero,
    float* __restrict__ out)
{
    const unsigned idx = blockIdx.x * BLK + threadIdx.x;  // float4 index, no tail
    const unsigned row = idx / K4;                        // magic-div, wave-uniform

    const float s = scale[row];   // L1/L2 broadcast
    const float z = zero[row];

    const f32x4 xv = __builtin_nontemporal_load(
        reinterpret_cast<const f32x4*>(x) + idx);

    f32x4 o;
    o.x = dq1(xv.x, s, z);
    o.y = dq1(xv.y, s, z);
    o.z = dq1(xv.z, s, z);
    o.w = dq1(xv.w, s, z);

    __builtin_nontemporal_store(o, reinterpret_cast<f32x4*>(out) + idx);
}

extern "C" void kernel_launch(void* const* d_in, const int* in_sizes, int n_in,
                              void* d_out, int out_size, void* d_ws, size_t ws_size,
                              hipStream_t stream) {
    const float* x     = (const float*)d_in[0];
    const float* scale = (const float*)d_in[1];
    const float* zero  = (const float*)d_in[2];
    // d_in[3] = codebook (values baked in), d_in[4] = maxq (=31)
    float* out = (float*)d_out;

    nlq_kernel<<<dim3(GRID), dim3(BLK), 0, stream>>>(x, scale, zero, out);
}